// Round 18
// baseline (414.165 us; speedup 1.0000x reference)
//
#include <hip/hip_runtime.h>

#define N_NODES 100000
#define N_EDGES 3200000
#define F_IN 128
#define HID 64
#define N_CLASS 40
#define ZROW N_NODES       // sentinel zero-row index

#define NBUCK 196          // ceil(100000/512)
#define BSHIFT 9
#define NBLK_A 512
#define CHUNK_A ((N_EDGES + NBLK_A - 1) / NBLK_A)

typedef float f32x2 __attribute__((ext_vector_type(2)));

template<bool HI>
static __device__ __forceinline__ int enc2_fp8(float a, float b, int old) {
    return __builtin_amdgcn_cvt_pk_fp8_f32(a, b, old, HI);   // HI is a constant expr
}
static __device__ __forceinline__ unsigned char enc_fp8(float v) {
    return (unsigned char)(__builtin_amdgcn_cvt_pk_fp8_f32(v, v, 0, false) & 0xff);
}

// gather 8 fp8 bytes: byteoff = row<<6 (pre-shifted), seg in [0,8)
static __device__ __forceinline__ uint2 gat8(const unsigned char* base, int byteoff, int seg) {
    return *(const uint2*)(base + ((unsigned)byteoff | (unsigned)(seg << 3)));
}

// decode 8 fp8 (uint2), packed-f32 accumulate
#define CONS(RAW) do { \
    f32x2 f0 = __builtin_amdgcn_cvt_pk_f32_fp8((int)RAW.x, false); \
    f32x2 f1 = __builtin_amdgcn_cvt_pk_f32_fp8((int)RAW.x, true); \
    f32x2 f2 = __builtin_amdgcn_cvt_pk_f32_fp8((int)RAW.y, false); \
    f32x2 f3 = __builtin_amdgcn_cvt_pk_f32_fp8((int)RAW.y, true); \
    a01 += f0; a23 += f1; a45 += f2; a67 += f3; } while (0)

// pipelined slot: issue gather for ib=bb+6+s using idx C (loaded last pass),
// reload C for pass+2, consume G
#define SLOT(s, G, C) { \
    int ib = bb + 6 + s; \
    int srcr = (ib < nb) ? C : zb; \
    uint2 ng = gat8(gsrc, srcr, seg); \
    C = sp[bb * 8 + 96 + s * 8]; \
    __builtin_amdgcn_sched_barrier(0); \
    CONS(G); \
    G = ng; }

// gather phase: accumulate over all in-edges into a01..a67, reduce across e-groups.
// after this, e==0 lanes hold features seg*8+0..7 in a01..a67.
#define GATHER_PHASE(TBL) \
    f32x2 a01 = {0.f, 0.f}, a23 = {0.f, 0.f}, a45 = {0.f, 0.f}, a67 = {0.f, 0.f}; \
    { \
        const unsigned char* gsrc = TBL; \
        int nb = pdeg[node] >> 3; \
        const int* sp = srow + start + e; \
        const int zb = ZROW << 6; \
        if (nb > 0) { \
            int c0 = sp[0],  c1 = sp[8],  c2 = sp[16], c3 = sp[24], c4 = sp[32], c5 = sp[40]; \
            uint2 g0 = gat8(gsrc, (0 < nb) ? c0 : zb, seg); \
            uint2 g1 = gat8(gsrc, (1 < nb) ? c1 : zb, seg); \
            uint2 g2 = gat8(gsrc, (2 < nb) ? c2 : zb, seg); \
            uint2 g3 = gat8(gsrc, (3 < nb) ? c3 : zb, seg); \
            uint2 g4 = gat8(gsrc, (4 < nb) ? c4 : zb, seg); \
            uint2 g5 = gat8(gsrc, (5 < nb) ? c5 : zb, seg); \
            c0 = sp[48]; c1 = sp[56]; c2 = sp[64]; c3 = sp[72]; c4 = sp[80]; c5 = sp[88]; \
            for (int bb = 0; bb < nb; bb += 6) { \
                SLOT(0, g0, c0) SLOT(1, g1, c1) SLOT(2, g2, c2) \
                SLOT(3, g3, c3) SLOT(4, g4, c4) SLOT(5, g5, c5) \
            } \
        } \
        if (e == 0) {  /* self term, counted once */ \
            uint2 sg = gat8(gsrc, node << 6, seg); \
            CONS(sg); \
        } \
    } \
    _Pragma("unroll") \
    for (int mm = 8; mm < 64; mm <<= 1) { \
        a01.x += __shfl_xor(a01.x, mm); a01.y += __shfl_xor(a01.y, mm); \
        a23.x += __shfl_xor(a23.x, mm); a23.y += __shfl_xor(a23.y, mm); \
        a45.x += __shfl_xor(a45.x, mm); a45.y += __shfl_xor(a45.y, mm); \
        a67.x += __shfl_xor(a67.x, mm); a67.y += __shfl_xor(a67.y, mm); \
    }

// ---------------- Phase A1: per-block bucket histogram (transposed out) ----------------
__global__ __launch_bounds__(256) void k_A1(const int* __restrict__ col, int* __restrict__ ghistT) {
    __shared__ int hist[256];
    int t = threadIdx.x;
    hist[t] = 0;
    __syncthreads();
    int e0 = blockIdx.x * CHUNK_A;
    int e1 = e0 + CHUNK_A; if (e1 > N_EDGES) e1 = N_EDGES;
    for (int e = e0 + t; e < e1; e += 256) {
        atomicAdd(&hist[col[e] >> BSHIFT], 1);
    }
    __syncthreads();
    ghistT[t * NBLK_A + blockIdx.x] = hist[t];
}

// ---------------- Phase A2a: per-bucket scan over 512 A-blocks ----------------
__global__ __launch_bounds__(256) void k_A2a(const int* __restrict__ ghistT, int* __restrict__ goffT,
                                             int* __restrict__ tot) {
    __shared__ int s[256];
    int b = blockIdx.x, t = threadIdx.x;
    int2 v = ((const int2*)(ghistT + b * NBLK_A))[t];
    int pair = v.x + v.y;
    s[t] = pair;
    __syncthreads();
    for (int d = 1; d < 256; d <<= 1) {
        int o = (t >= d) ? s[t - d] : 0;
        __syncthreads();
        s[t] += o;
        __syncthreads();
    }
    int incl = s[t];
    int excl = incl - pair;
    goffT[b * NBLK_A + 2 * t]     = excl;
    goffT[b * NBLK_A + 2 * t + 1] = excl + v.x;
    if (t == 255) tot[b] = incl;
}

// ---------------- Phase A2b: scan of bucket totals (+ zero sentinel rows) ----------------
__global__ __launch_bounds__(256) void k_A2b(const int* __restrict__ tot, int* __restrict__ bbase,
                                             int* __restrict__ bend,
                                             unsigned char* __restrict__ h1q,
                                             unsigned char* __restrict__ o1q) {
    __shared__ int s[256];
    int t = threadIdx.x;
    int v = tot[t];
    s[t] = v;
    __syncthreads();
    for (int d = 1; d < 256; d <<= 1) {
        int o = (t >= d) ? s[t - d] : 0;
        __syncthreads();
        s[t] += o;
        __syncthreads();
    }
    bbase[t] = s[t] - v;
    bend[t] = s[t];
    if (t < 64) h1q[(size_t)ZROW * 64 + t] = 0;
    else if (t < 128) o1q[(size_t)ZROW * 64 + (t - 64)] = 0;
}

// ---------------- Phase A3: coalesced-reserved bucket scatter ----------------
__global__ __launch_bounds__(256) void k_A3(const int* __restrict__ row, const int* __restrict__ col,
                                            const int* __restrict__ goffT, const int* __restrict__ bbase,
                                            unsigned int* __restrict__ epair) {
    __shared__ int cur[256];
    int t = threadIdx.x;
    cur[t] = goffT[t * NBLK_A + blockIdx.x] + bbase[t];
    __syncthreads();
    int e0 = blockIdx.x * CHUNK_A;
    int e1 = e0 + CHUNK_A; if (e1 > N_EDGES) e1 = N_EDGES;
    for (int e = e0 + t; e < e1; e += 256) {
        int c = col[e];
        int pos = atomicAdd(&cur[c >> BSHIFT], 1);
        epair[pos] = ((unsigned int)(c & 511) << 17) | (unsigned int)row[e];
    }
}

// ---------------- Phase B: per-bucket CSR build; srow holds (row<<6) byte offsets ----------------
__global__ __launch_bounds__(256) void k_B(const unsigned int* __restrict__ epair,
                                           const int* __restrict__ bbase, const int* __restrict__ bend,
                                           int* __restrict__ off, int* __restrict__ pdeg,
                                           float* __restrict__ dinv, int* __restrict__ srow) {
    __shared__ int h[512];
    __shared__ int psc[256];
    int t = threadIdx.x;
    int b = blockIdx.x;
    int n0 = b << BSHIFT;
    int e0 = bbase[b], e1 = bend[b];
    int pbase = e0 + b * 4096;
    h[t] = 0; h[t + 256] = 0;
    __syncthreads();
    for (int e = e0 + t; e < e1; e += 256) {
        atomicAdd(&h[epair[e] >> 17], 1);
    }
    __syncthreads();
    int a0 = h[2 * t], a1 = h[2 * t + 1];
    int p0 = (a0 + 7) & ~7, p1 = (a1 + 7) & ~7;
    psc[t] = p0 + p1;
    __syncthreads();
    for (int d = 1; d < 256; d <<= 1) {
        int o = (t >= d) ? psc[t - d] : 0;
        __syncthreads();
        psc[t] += o;
        __syncthreads();
    }
    int base0 = pbase + psc[t] - (p0 + p1);
    int base1 = base0 + p0;
    h[2 * t] = base0;
    h[2 * t + 1] = base1;
    int n = n0 + 2 * t;
    const int zb = ZROW << 6;
    if (n < N_NODES) {
        off[n] = base0; pdeg[n] = p0; dinv[n] = rsqrtf((float)a0 + 1.0f);
        for (int p = a0; p < p0; ++p) srow[base0 + p] = zb;
    }
    if (n + 1 < N_NODES) {
        off[n + 1] = base1; pdeg[n + 1] = p1; dinv[n + 1] = rsqrtf((float)a1 + 1.0f);
        for (int p = a1; p < p1; ++p) srow[base1 + p] = zb;
    }
    __syncthreads();
    for (int e = e0 + t; e < e1; e += 256) {
        unsigned int k = epair[e];
        int c = k >> 17;
        int pos = atomicAdd(&h[c], 1);
        srow[pos] = (int)(k & 0x1FFFFu) << 6;
    }
}

// ---------------- tiled dense GEMM (layer 1): O = fp8(scale[n]*(X @ W^T)) ----------------
template<int K, int C, int ROWS_PB>
__global__ __launch_bounds__(256, 4) void k_gemm(const float* __restrict__ X, const float* __restrict__ W,
                                                 const float* __restrict__ scale, unsigned char* __restrict__ O) {
    constexpr int PK = K + 4;
    __shared__ float ws[C * PK];
    __shared__ float xs[32 * PK];
    int t = threadIdx.x;
    for (int i4 = t; i4 < C * K / 4; i4 += 256) {
        int j = i4 / (K / 4);
        int k4 = i4 % (K / 4);
        float4 v = ((const float4*)W)[i4];
        *(float4*)&ws[j * PK + k4 * 4] = v;
    }
    int j = t & 63;
    int r0 = (t >> 6) * 8;
    int rowbase = blockIdx.x * ROWS_PB;
    for (int chunk = 0; chunk < ROWS_PB; chunk += 32) {
        int cb = rowbase + chunk;
        __syncthreads();
        for (int i4 = t; i4 < 32 * K / 4; i4 += 256) {
            int r = i4 / (K / 4);
            int k4 = i4 % (K / 4);
            int rr = cb + r;
            float4 v = make_float4(0.f, 0.f, 0.f, 0.f);
            if (rr < N_NODES) v = ((const float4*)X)[(size_t)rr * (K / 4) + k4];
            *(float4*)&xs[r * PK + k4 * 4] = v;
        }
        __syncthreads();
        if (j < C) {
            float acc[8] = {0.f, 0.f, 0.f, 0.f, 0.f, 0.f, 0.f, 0.f};
#pragma unroll 2
            for (int k4 = 0; k4 < K / 4; ++k4) {
                float4 wv = *(const float4*)&ws[j * PK + k4 * 4];
#pragma unroll
                for (int r = 0; r < 8; ++r) {
                    float4 xv = *(const float4*)&xs[(r0 + r) * PK + k4 * 4];
                    acc[r] += xv.x * wv.x + xv.y * wv.y + xv.z * wv.z + xv.w * wv.w;
                }
            }
#pragma unroll
            for (int r = 0; r < 8; ++r) {
                int rr = cb + r0 + r;
                if (rr < N_NODES) O[(size_t)rr * 64 + j] = enc_fp8(acc[r] * scale[rr]);
            }
        }
    }
}

// ---------------- layer-1 aggregation: no-LDS, direct-index pipelined gathers ----------------
__global__ __launch_bounds__(256) void k_agg1(const int* __restrict__ off, const int* __restrict__ pdeg,
                                              const int* __restrict__ srow, const float* __restrict__ dinv,
                                              const unsigned char* __restrict__ h1q, const float* __restrict__ b1,
                                              unsigned char* __restrict__ o1q) {
    int t = threadIdx.x;
    int node = (blockIdx.x * 256 + t) >> 6;
    int lane = t & 63;
    int e = lane >> 3, seg = lane & 7;
    int start = off[node];
    GATHER_PHASE(h1q)
    if (e == 0) {
        float dc = dinv[node];
        float4 ba = *(const float4*)(b1 + seg * 8);
        float4 bb4 = *(const float4*)(b1 + seg * 8 + 4);
        float v0 = dc * a01.x + ba.x,  v1 = dc * a01.y + ba.y;
        float v2 = dc * a23.x + ba.z,  v3 = dc * a23.y + ba.w;
        float v4 = dc * a45.x + bb4.x, v5 = dc * a45.y + bb4.y;
        float v6 = dc * a67.x + bb4.z, v7 = dc * a67.y + bb4.w;
        float s16 = 16.f * dc;
        v0 = v0 > 0.f ? v0 * s16 : 0.f; v1 = v1 > 0.f ? v1 * s16 : 0.f;
        v2 = v2 > 0.f ? v2 * s16 : 0.f; v3 = v3 > 0.f ? v3 * s16 : 0.f;
        v4 = v4 > 0.f ? v4 * s16 : 0.f; v5 = v5 > 0.f ? v5 * s16 : 0.f;
        v6 = v6 > 0.f ? v6 * s16 : 0.f; v7 = v7 > 0.f ? v7 * s16 : 0.f;
        uint2 pk;
        pk.x = (unsigned)enc2_fp8<true>(v2, v3, enc2_fp8<false>(v0, v1, 0));
        pk.y = (unsigned)enc2_fp8<true>(v6, v7, enc2_fp8<false>(v4, v5, 0));
        *(uint2*)(o1q + (((unsigned)node << 6) | (unsigned)(seg << 3))) = pk;
    }
}

// ---------------- layer-2: pipelined gather + fused W2 matvec + softmax ----------------
__global__ __launch_bounds__(256) void k_agg2(const int* __restrict__ off, const int* __restrict__ pdeg,
                                              const int* __restrict__ srow, const float* __restrict__ dinv,
                                              const unsigned char* __restrict__ o1q,
                                              const float* __restrict__ W2, const float* __restrict__ b2,
                                              const int* __restrict__ y,
                                              float* __restrict__ out, unsigned short* __restrict__ ps) {
    __shared__ __align__(16) float w2s[N_CLASS * 68];   // w2s[c*68+k] = W2[c][k]/16
    __shared__ __align__(16) float sh[4][64];
    int t = threadIdx.x;
    for (int i = t; i < HID * N_CLASS; i += 256) {
        int c = i >> 6, k = i & 63;
        w2s[c * 68 + k] = W2[i] * 0.0625f;
    }
    int node = (blockIdx.x * 256 + t) >> 6;
    int lane = t & 63, wid = t >> 6;
    int e = lane >> 3, seg = lane & 7;
    int start = off[node];
    GATHER_PHASE(o1q)
    if (e == 0) {
        *(f32x2*)&sh[wid][seg * 8 + 0] = a01;
        *(f32x2*)&sh[wid][seg * 8 + 2] = a23;
        *(f32x2*)&sh[wid][seg * 8 + 4] = a45;
        *(f32x2*)&sh[wid][seg * 8 + 6] = a67;
    }
    __syncthreads();   // covers w2s staging + sh transpose
    bool act = lane < N_CLASS;
    int cl = act ? lane : N_CLASS - 1;
    float mv = 0.f;
#pragma unroll
    for (int k4 = 0; k4 < HID / 4; ++k4) {
        float4 sv = *(const float4*)&sh[wid][k4 * 4];
        float4 wv = *(const float4*)&w2s[cl * 68 + k4 * 4];
        mv += sv.x * wv.x + sv.y * wv.y + sv.z * wv.z + sv.w * wv.w;
    }
    float dc = dinv[node];
    float v = act ? (dc * mv + b2[lane]) : -1e30f;
    // merged max + argmax reduction
    float m = v;
    int ai = act ? lane : 64;
#pragma unroll
    for (int k = 1; k < 64; k <<= 1) {
        float ov = __shfl_xor(m, k);
        int oi = __shfl_xor(ai, k);
        if (ov > m || (ov == m && oi < ai)) { m = ov; ai = oi; }
    }
    float sv2 = act ? expf(v - m) : 0.f;
    float s = sv2;
#pragma unroll
    for (int k = 1; k < 64; k <<= 1) s += __shfl_xor(s, k);
    float ls = logf(s);
    if (act) {
        float lp = (v - m) - ls;
        float* logp = out;
        float* p = out + (size_t)N_NODES * N_CLASS;
        logp[(size_t)node * N_CLASS + lane] = lp;
        p[(size_t)node * N_CLASS + lane] = expf(lp);
    }
    if (lane == 0) ps[node] = (unsigned short)((y[node] << 8) | ai);
}

// ---------------- ratio over original edges (8 edges / iter) ----------------
__global__ __launch_bounds__(256) void k_ratio(const int* __restrict__ row, const int* __restrict__ col,
                                               const unsigned short* __restrict__ ps,
                                               unsigned int* __restrict__ cnt) {
    int i = blockIdx.x * 256 + threadIdx.x;
    int stride = gridDim.x * 256;
    unsigned int local = 0;
    for (int e8 = i; e8 < N_EDGES / 8; e8 += stride) {
        int4 ra = ((const int4*)row)[e8 * 2];
        int4 rb = ((const int4*)row)[e8 * 2 + 1];
        int4 ca = ((const int4*)col)[e8 * 2];
        int4 cb = ((const int4*)col)[e8 * 2 + 1];
        unsigned int pa[8], pb[8];
        pa[0] = ps[ra.x]; pa[1] = ps[ra.y]; pa[2] = ps[ra.z]; pa[3] = ps[ra.w];
        pa[4] = ps[rb.x]; pa[5] = ps[rb.y]; pa[6] = ps[rb.z]; pa[7] = ps[rb.w];
        pb[0] = ps[ca.x]; pb[1] = ps[ca.y]; pb[2] = ps[ca.z]; pb[3] = ps[ca.w];
        pb[4] = ps[cb.x]; pb[5] = ps[cb.y]; pb[6] = ps[cb.z]; pb[7] = ps[cb.w];
#pragma unroll
        for (int k = 0; k < 8; ++k) {
            bool sp = (pa[k] & 0xffu) == (pb[k] & 0xffu);
            bool sy = (pa[k] >> 8) == (pb[k] >> 8);
            local += (sp == sy) ? 1u : 0u;
        }
    }
    if (local) atomicAdd(cnt, local);
}

__global__ void k_fin(const unsigned int* __restrict__ cnt, float* __restrict__ out) {
    out[0] = (float)(*cnt) / (float)N_EDGES;
}

extern "C" void kernel_launch(void* const* d_in, const int* in_sizes, int n_in,
                              void* d_out, int out_size, void* d_ws, size_t ws_size,
                              hipStream_t stream) {
    const float* x  = (const float*)d_in[0];
    const int*   ei = (const int*)d_in[1];
    const int*   y  = (const int*)d_in[2];
    const float* W1 = (const float*)d_in[3];
    const float* b1 = (const float*)d_in[4];
    const float* W2 = (const float*)d_in[5];
    const float* b2 = (const float*)d_in[6];

    const int* row = ei;
    const int* col = ei + N_EDGES;

    float* ws = (float*)d_ws;
    // workspace layout (4B units); fp8 tables have N_NODES+1 rows (sentinel)
    unsigned char* h1q = (unsigned char*)ws;               // (N+1)*64 B
    unsigned char* o1q = (unsigned char*)(ws + 1700000);   // (N+1)*64 B
    float* dinv   = ws + 3400000;                   // N
    int*   pdeg   = (int*)(ws + 3500000);           // N
    int*   off    = (int*)(ws + 3600000);           // N
    int*   srow   = (int*)(ws + 3700000);           // padded CSR (~4.0M) + tail slack
    int*   ghistT = (int*)(ws + 7800000);           // 256*512 (bucket-major)
    int*   goffT  = (int*)(ws + 8000000);           // 256*512
    int*   tot    = (int*)(ws + 8150000);           // 256
    int*   bbase  = (int*)(ws + 8200000);           // 256
    int*   bend   = (int*)(ws + 8201000);           // 256
    unsigned short* ps = (unsigned short*)(ws + 8210000);  // N ushort
    unsigned int* cnt  = (unsigned int*)(ws + 8300000);
    unsigned int* epair = (unsigned int*)(ws + 8400000);   // E uint32

    float* out = (float*)d_out;

    (void)hipMemsetAsync(cnt, 0, 4, stream);

    const int GEMM_GRID = (N_NODES + 127) / 128;
    const int AGG_GRID = (N_NODES * 64) / 256;      // exact: 25000

    k_A1<<<NBLK_A, 256, 0, stream>>>(col, ghistT);
    k_A2a<<<256, 256, 0, stream>>>(ghistT, goffT, tot);
    k_A2b<<<1, 256, 0, stream>>>(tot, bbase, bend, h1q, o1q);
    k_A3<<<NBLK_A, 256, 0, stream>>>(row, col, goffT, bbase, epair);
    k_B<<<NBUCK, 256, 0, stream>>>(epair, bbase, bend, off, pdeg, dinv, srow);
    k_gemm<F_IN, HID, 128><<<GEMM_GRID, 256, 0, stream>>>(x, W1, dinv, h1q);
    k_agg1<<<AGG_GRID, 256, 0, stream>>>(off, pdeg, srow, dinv, h1q, b1, o1q);
    k_agg2<<<AGG_GRID, 256, 0, stream>>>(off, pdeg, srow, dinv, o1q, W2, b2, y, out, ps);
    k_ratio<<<2048, 256, 0, stream>>>(row, col, ps, cnt);
    k_fin<<<1, 1, 0, stream>>>(cnt, out + (size_t)2 * N_NODES * N_CLASS);
}